// Round 17
// baseline (185.472 us; speedup 1.0000x reference)
//
#include <hip/hip_runtime.h>
#include <hip/hip_fp16.h>

#define DIM 64
#define BN_EPS 1e-5f
#define RSHIFT 8          // 256 nodes per range
#define RSIZE 256
#define EPB 2048          // edges per bin2 block (512 thr x 4)
#define ABLK 2048         // aggregation blocks (stats partials per block)
#define RBLK 128          // stage-1 reduction blocks (ABLK/RBLK partials each)
#define BH 512            // meta row stride (bins per block record)

// ---------------- bin2: self-contained block-local counting sort into private pk region ----------------
// Reads src+dst ONCE. Each block groups its 2048 edges by dst-range inside LDS and writes them
// grouped into pk[blk*EPB ...]. meta[blk*BH+r] = (local_exclusive_offset<<12) | count.
__global__ __launch_bounds__(512) void k_bin2(const int* __restrict__ src,
                                              const int* __restrict__ dst,
                                              int* __restrict__ meta,
                                              int* __restrict__ pk, int P, int E) {
    __shared__ int hist[BH], ls[BH], lcur[BH];
    const int tid = threadIdx.x;
    hist[tid] = 0;
    __syncthreads();
    const int idx = blockIdx.x * 512 + tid;
    const int e0 = idx << 2;
    int d[4], s[4];
    int vc = 0;
    if (e0 + 3 < E) {
        int4 d4 = ((const int4*)dst)[idx];
        int4 s4 = ((const int4*)src)[idx];
        d[0] = d4.x; d[1] = d4.y; d[2] = d4.z; d[3] = d4.w;
        s[0] = s4.x; s[1] = s4.y; s[2] = s4.z; s[3] = s4.w;
        vc = 4;
    } else {
        for (int k = 0; k < 4; ++k)
            if (e0 + k < E) { d[vc] = dst[e0 + k]; s[vc] = src[e0 + k]; ++vc; }
    }
    for (int k = 0; k < vc; ++k) atomicAdd(&hist[d[k] >> RSHIFT], 1);
    __syncthreads();
    int cnt = hist[tid];
    ls[tid] = cnt;
    __syncthreads();
    for (int off = 1; off < 512; off <<= 1) {
        int t = (tid >= off) ? ls[tid - off] : 0;
        __syncthreads();
        ls[tid] += t;
        __syncthreads();
    }
    int lofs = ls[tid] - cnt;   // local exclusive
    lcur[tid] = lofs;
    if (tid < P) meta[blockIdx.x * BH + tid] = (lofs << 12) | cnt;  // lofs,cnt <= 2048 fit 12 bits
    __syncthreads();
    const int base = blockIdx.x * EPB;
    for (int k = 0; k < vc; ++k) {
        int b = d[k] >> RSHIFT;
        pk[base + atomicAdd(&lcur[b], 1)] = ((d[k] & (RSIZE - 1)) << 20) | s[k];
    }
}

// ---------------- binred: bintot[r] = sum over blocks of meta counts ----------------
__global__ __launch_bounds__(128) void k_binred(const int* __restrict__ meta,
                                                int* __restrict__ bintot, int nbin) {
    __shared__ int s[128];
    const int r = blockIdx.x;
    int acc = 0;
    for (int idx = threadIdx.x; idx < nbin; idx += 128)
        acc += meta[idx * BH + r] & 0xFFF;
    s[threadIdx.x] = acc;
    __syncthreads();
    for (int o = 64; o > 0; o >>= 1) {
        if ((int)threadIdx.x < o) s[threadIdx.x] += s[threadIdx.x + o];
        __syncthreads();
    }
    if (threadIdx.x == 0) bintot[r] = s[0];
}

// ---------------- gscan: exclusive scan of bintot (P <= 512) -> gbase ----------------
__global__ void k_gscan(const int* __restrict__ bintot, int* __restrict__ gbase,
                        int* __restrict__ rowptr, int P, int N, int E) {
    __shared__ int s[512];
    int v = ((int)threadIdx.x < P) ? bintot[threadIdx.x] : 0;
    s[threadIdx.x] = v;
    __syncthreads();
    for (int off = 1; off < 512; off <<= 1) {
        int t = (threadIdx.x >= (unsigned)off) ? s[threadIdx.x - off] : 0;
        __syncthreads();
        s[threadIdx.x] += t;
        __syncthreads();
    }
    if ((int)threadIdx.x < P) gbase[threadIdx.x] = s[threadIdx.x] - v;
    if ((int)threadIdx.x == P - 1) gbase[P] = s[threadIdx.x];  // = E
    if (threadIdx.x == 0) rowptr[N] = E;
}

// ---------------- sortrange: per-range counting sort over per-block pk slices ----------------
__global__ __launch_bounds__(512) void k_sortrange(
        const int* __restrict__ gbase, const int* __restrict__ meta,
        const int* __restrict__ pk, int* __restrict__ ssrc,
        int* __restrict__ rowptr, float* __restrict__ dinv, int N, int nbin) {
    __shared__ int lhist[256], ls[256], lcur[256];
    const int r = blockIdx.x;
    const int d0 = r << RSHIFT;
    const int tid = threadIdx.x;
    const int ebeg = gbase[r];
    if (tid < 256) lhist[tid] = 0;
    __syncthreads();
    // phase A: node histogram from this range's per-block slices
    for (int blk = tid; blk < nbin; blk += 512) {
        int m = meta[blk * BH + r];
        int cnt = m & 0xFFF, lofs = (m >> 12) & 0xFFF;
        const int* p = pk + blk * EPB + lofs;
        for (int i = 0; i < cnt; ++i)
            atomicAdd(&lhist[((unsigned)p[i]) >> 20], 1);
    }
    __syncthreads();
    int dg = 0;
    if (tid < 256) {
        dg = lhist[tid];
        int i = d0 + tid;
        if (i < N) dinv[i] = rsqrtf((float)dg + 1.0f);  // +1 self-loop
        ls[tid] = dg;
    }
    __syncthreads();
    for (int off = 1; off < 256; off <<= 1) {
        int t = (tid < 256 && tid >= off) ? ls[tid - off] : 0;
        __syncthreads();
        if (tid < 256) ls[tid] += t;
        __syncthreads();
    }
    if (tid < 256) {
        int lofs = ls[tid] - dg;      // local exclusive
        lcur[tid] = ebeg + lofs;      // absolute cursor
        int i = d0 + tid;
        if (i < N) rowptr[i] = ebeg + lofs;
    }
    __syncthreads();
    // phase B: scatter into node-sorted ssrc
    for (int blk = tid; blk < nbin; blk += 512) {
        int m = meta[blk * BH + r];
        int cnt = m & 0xFFF, lofs = (m >> 12) & 0xFFF;
        const int* p = pk + blk * EPB + lofs;
        for (int i = 0; i < cnt; ++i) {
            int v = p[i];
            ssrc[atomicAdd(&lcur[((unsigned)v) >> 20], 1)] = v & 0xFFFFF;
        }
    }
}

// ---------------- gemm: 4 threads/row, 16 outputs each; emit h2 = fp16(h*dinv) only ----------------
__global__ __launch_bounds__(256) void k_gemm(const float* __restrict__ x,
                                              const float* __restrict__ W,
                                              const float* __restrict__ dinv,
                                              __half* __restrict__ h2, int N) {
    __shared__ float Wl[DIM * DIM];
    for (int i = threadIdx.x; i < DIM * DIM; i += 256) Wl[i] = W[i];
    __syncthreads();
    int t = blockIdx.x * 256 + threadIdx.x;
    int r = t >> 2;       // row
    int q = t & 3;        // output-feature quarter
    if (r >= N) return;
    const float4* xr4 = (const float4*)(x + (size_t)r * DIM);
    float4 acc[4];
#pragma unroll
    for (int j = 0; j < 4; ++j) acc[j] = make_float4(0.f, 0.f, 0.f, 0.f);
    for (int k0 = 0; k0 < 16; ++k0) {
        float4 xv = xr4[k0];
#pragma unroll
        for (int kk = 0; kk < 4; ++kk) {
            float xs = (&xv.x)[kk];
            const float4* wrow = (const float4*)(Wl + (k0 * 4 + kk) * DIM) + (q << 2);
#pragma unroll
            for (int j = 0; j < 4; ++j) {
                float4 w = wrow[j];
                acc[j].x += xs * w.x;
                acc[j].y += xs * w.y;
                acc[j].z += xs * w.z;
                acc[j].w += xs * w.w;
            }
        }
    }
    float dr = dinv[r];
    float4* hr4 = (float4*)(h2 + (size_t)r * DIM) + (q << 1);
    union { __half2 h[4]; float4 f4; } pack;
#pragma unroll
    for (int j = 0; j < 4; j += 2) {
        pack.h[0] = __float22half2_rn(make_float2(acc[j].x * dr, acc[j].y * dr));
        pack.h[1] = __float22half2_rn(make_float2(acc[j].z * dr, acc[j].w * dr));
        pack.h[2] = __float22half2_rn(make_float2(acc[j + 1].x * dr, acc[j + 1].y * dr));
        pack.h[3] = __float22half2_rn(make_float2(acc[j + 1].z * dr, acc[j + 1].w * dr));
        hr4[j >> 1] = pack.f4;
    }
}

// ---------------- nodeagg: node-PAIR pull; 16/8/4/1 gather cascade (no clamp waste) ----------------
#define GATHER_BATCH(B)                                                             \
    {                                                                               \
        int sA[B]; float vA[B];                                                     \
        _Pragma("unroll")                                                           \
        for (int k = 0; k < B; ++k) sA[k] = __builtin_amdgcn_readlane(sv, j + k);   \
        _Pragma("unroll")                                                           \
        for (int k = 0; k < B; ++k) vA[k] = __half2float(hb[(size_t)sA[k] * DIM]);  \
        _Pragma("unroll")                                                           \
        for (int k = 0; k < B; ++k) {                                               \
            if (j + k < c) acc0 += vA[k]; else acc1 += vA[k];                       \
        }                                                                           \
        j += B;                                                                     \
    }

__global__ __launch_bounds__(256) void k_nodeagg(
        const int* __restrict__ rowptr, const int* __restrict__ ssrc,
        const __half* __restrict__ h2, const float* __restrict__ dinv,
        const float* __restrict__ b, __half* __restrict__ a2,
        float* __restrict__ pstats, int N) {
    const int lane = threadIdx.x & 63;
    const int w = threadIdx.x >> 6;
    const float bl = b[lane];
    const __half* hb = h2 + lane;
    float psum = 0.f, psq = 0.f;
    const int npairs = N >> 1;  // N even (100000)
    for (int t = blockIdx.x * 4 + w; t < npairs; t += ABLK * 4) {
        const int i0 = t << 1;
        const int rb0 = rowptr[i0], rb1 = rowptr[i0 + 1], rb2 = rowptr[i0 + 2];
        float acc0 = __half2float(hb[(size_t)i0 * DIM]);        // self term node0
        float acc1 = __half2float(hb[(size_t)(i0 + 1) * DIM]);  // self term node1
        const int total = rb2 - rb0;
        for (int j0 = 0; j0 < total; j0 += 64) {
            const int m = min(64, total - j0);
            const int c = rb1 - rb0 - j0;   // local boundary (wave-uniform)
            int sv = ssrc[rb0 + j0 + min(lane, m - 1)];
            int j = 0;
            while (j + 16 <= m) GATHER_BATCH(16)
            if (j + 8 <= m) GATHER_BATCH(8)
            if (j + 4 <= m) GATHER_BATCH(4)
            for (; j < m; ++j) {
                int sj = __builtin_amdgcn_readlane(sv, j);
                float v = __half2float(hb[(size_t)sj * DIM]);
                if (j < c) acc0 += v; else acc1 += v;
            }
        }
        float a0 = fmaxf(acc0 * dinv[i0] + bl, 0.f);
        float a1 = fmaxf(acc1 * dinv[i0 + 1] + bl, 0.f);
        a2[(size_t)i0 * DIM + lane] = __float2half_rn(a0);
        a2[(size_t)(i0 + 1) * DIM + lane] = __float2half_rn(a1);
        psum += a0 + a1;
        psq += a0 * a0 + a1 * a1;
    }
    __shared__ float s1[256], s2[256];
    s1[threadIdx.x] = psum;
    s2[threadIdx.x] = psq;
    __syncthreads();
    if (threadIdx.x < 128) {
        s1[threadIdx.x] += s1[threadIdx.x + 128];
        s2[threadIdx.x] += s2[threadIdx.x + 128];
    }
    __syncthreads();
    if (threadIdx.x < 64) {
        pstats[(size_t)blockIdx.x * 128 + threadIdx.x] = s1[threadIdx.x] + s1[threadIdx.x + 64];
        pstats[(size_t)blockIdx.x * 128 + 64 + threadIdx.x] = s2[threadIdx.x] + s2[threadIdx.x + 64];
    }
}

// ---------------- redstats: stage-1 parallel fold of ABLK partials -> RBLK partials ----------------
__global__ __launch_bounds__(128) void k_redstats(const float* __restrict__ pstats,
                                                  float* __restrict__ pstats2) {
    const int f = threadIdx.x;
    const size_t base = (size_t)blockIdx.x * (ABLK / RBLK) * 128;
    float s = 0.f;
#pragma unroll 8
    for (int j = 0; j < ABLK / RBLK; ++j)
        s += pstats[base + (size_t)j * 128 + f];
    pstats2[(size_t)blockIdx.x * 128 + f] = s;
}

// ---------------- finstats: reduce RBLK partials, emit scale/shift ----------------
__global__ void k_finstats(const float* __restrict__ pstats2,
                           const float* __restrict__ gamma, const float* __restrict__ beta,
                           float* __restrict__ scale, float* __restrict__ shift, int N) {
    __shared__ float ssum[1024], ssq[1024];
    const int f = threadIdx.x & 63;
    const int c = threadIdx.x >> 6;  // 0..15
    float s = 0.f, q = 0.f;
    for (int blk = c; blk < RBLK; blk += 16) {
        s += pstats2[blk * 128 + f];
        q += pstats2[blk * 128 + 64 + f];
    }
    ssum[threadIdx.x] = s;
    ssq[threadIdx.x] = q;
    __syncthreads();
    for (int o = 512; o >= 64; o >>= 1) {
        if ((int)threadIdx.x < o) {
            ssum[threadIdx.x] += ssum[threadIdx.x + o];
            ssq[threadIdx.x] += ssq[threadIdx.x + o];
        }
        __syncthreads();
    }
    if (threadIdx.x < 64) {
        float inv_n = 1.0f / (float)N;
        float mean = ssum[f] * inv_n;
        float var = ssq[f] * inv_n - mean * mean;
        float istd = rsqrtf(var + BN_EPS);
        float sc = gamma[f] * istd;
        scale[f] = sc;
        shift[f] = beta[f] - mean * sc;
    }
}

// ---------------- bn2: out = a2*scale + shift (a2 fp16, already relu'd) ----------------
__global__ void k_bn2(const __half* __restrict__ a2, const float* __restrict__ scale,
                      const float* __restrict__ shift, float* __restrict__ out, int total8) {
    int i = blockIdx.x * blockDim.x + threadIdx.x;
    const int stride = gridDim.x * blockDim.x;  // 262144 ≡ 0 (mod 8)
    const int f8 = i & 7;
    const float4 sc0 = ((const float4*)scale)[f8 * 2];
    const float4 sc1 = ((const float4*)scale)[f8 * 2 + 1];
    const float4 sh0 = ((const float4*)shift)[f8 * 2];
    const float4 sh1 = ((const float4*)shift)[f8 * 2 + 1];
    for (; i < total8; i += stride) {
        union { float4 f; __half2 h[4]; } u;
        u.f = ((const float4*)a2)[i];
        float2 p0 = __half22float2(u.h[0]);
        float2 p1 = __half22float2(u.h[1]);
        float2 p2 = __half22float2(u.h[2]);
        float2 p3 = __half22float2(u.h[3]);
        float4 o0 = make_float4(p0.x * sc0.x + sh0.x, p0.y * sc0.y + sh0.y,
                                p1.x * sc0.z + sh0.z, p1.y * sc0.w + sh0.w);
        float4 o1 = make_float4(p2.x * sc1.x + sh1.x, p2.y * sc1.y + sh1.y,
                                p3.x * sc1.z + sh1.z, p3.y * sc1.w + sh1.w);
        ((float4*)out)[(size_t)i * 2] = o0;
        ((float4*)out)[(size_t)i * 2 + 1] = o1;
    }
}

extern "C" void kernel_launch(void* const* d_in, const int* in_sizes, int n_in,
                              void* d_out, int out_size, void* d_ws, size_t ws_size,
                              hipStream_t stream) {
    const float* x     = (const float*)d_in[0];
    const int*   ei    = (const int*)d_in[1];
    const float* W     = (const float*)d_in[2];
    const float* b     = (const float*)d_in[3];
    const float* gamma = (const float*)d_in[4];
    const float* beta  = (const float*)d_in[5];
    float* out = (float*)d_out;

    const int N = in_sizes[0] / DIM;  // 100000
    const int E = in_sizes[1] / 2;    // 1000000
    const int* esrc = ei;
    const int* edst = ei + E;
    const int P = (N + RSIZE - 1) >> RSHIFT;   // 391 ranges (<= 512)
    const int nbin = (E + EPB - 1) / EPB;      // 489 bin2 blocks (<= 512)

    // workspace layout
    char* ws = (char*)d_ws;
    size_t off = 0;
    int* meta = (int*)(ws + off);       off += (size_t)nbin * BH * sizeof(int);  // (lofs<<12)|cnt
    off = (off + 255) & ~(size_t)255;
    int* bintot = (int*)(ws + off);     off += 512 * sizeof(int);
    int* gbase = (int*)(ws + off);      off += 520 * sizeof(int);
    off = (off + 255) & ~(size_t)255;
    float* dinv = (float*)(ws + off);   off += (size_t)N * sizeof(float);
    off = (off + 255) & ~(size_t)255;
    int* rowptr = (int*)(ws + off);     off += (size_t)(N + 1) * sizeof(int);
    off = (off + 255) & ~(size_t)255;
    float* scale = (float*)(ws + off);  off += 64 * sizeof(float);
    float* shift = (float*)(ws + off);  off += 64 * sizeof(float);
    off = (off + 255) & ~(size_t)255;
    float* pstats = (float*)(ws + off); off += (size_t)ABLK * 128 * sizeof(float);
    off = (off + 255) & ~(size_t)255;
    float* pstats2 = (float*)(ws + off); off += (size_t)RBLK * 128 * sizeof(float);
    off = (off + 255) & ~(size_t)255;
    int* pk = (int*)(ws + off);         off += (size_t)nbin * EPB * sizeof(int);  // private per-block regions
    off = (off + 255) & ~(size_t)255;
    int* ssrc = (int*)(ws + off);       off += (size_t)E * sizeof(int);
    off = (off + 255) & ~(size_t)255;
    __half* h2 = (__half*)(ws + off);   off += (size_t)N * DIM * sizeof(__half);
    off = (off + 255) & ~(size_t)255;
    __half* a2 = (__half*)(ws + off);   off += (size_t)N * DIM * sizeof(__half);

    k_bin2<<<nbin, 512, 0, stream>>>(esrc, edst, meta, pk, P, E);
    k_binred<<<P, 128, 0, stream>>>(meta, bintot, nbin);
    k_gscan<<<1, 512, 0, stream>>>(bintot, gbase, rowptr, P, N, E);
    k_sortrange<<<P, 512, 0, stream>>>(gbase, meta, pk, ssrc, rowptr, dinv, N, nbin);
    k_gemm<<<(4 * N + 255) / 256, 256, 0, stream>>>(x, W, dinv, h2, N);
    k_nodeagg<<<ABLK, 256, 0, stream>>>(rowptr, ssrc, h2, dinv, b, a2, pstats, N);
    k_redstats<<<RBLK, 128, 0, stream>>>(pstats, pstats2);
    k_finstats<<<1, 1024, 0, stream>>>(pstats2, gamma, beta, scale, shift, N);
    k_bn2<<<1024, 256, 0, stream>>>(a2, scale, shift, out, N * DIM / 8);
}

// Round 18
// 182.823 us; speedup vs baseline: 1.0145x; 1.0145x over previous
//
#include <hip/hip_runtime.h>
#include <hip/hip_fp16.h>

#define DIM 64
#define BN_EPS 1e-5f
#define RSHIFT 8          // 256 nodes per range
#define RSIZE 256
#define EPB 2048          // edges per bin block
#define ABLK 2048         // aggregation blocks (stats partials per block)
#define RBLK 128          // stage-1 reduction blocks (ABLK/RBLK partials each)
#define BH 512            // bhist row stride (bins per block record)

// ---------------- hist_gemm: FUSED independent kernels ----------------
// blocks [0, nbin): per-(block,bin) edge counts -> bhist (binhist body)
// blocks [nbin, nbin+gemmblocks): h2 = fp16(x @ W) UNSCALED (dinv applied at gather time)
__global__ __launch_bounds__(256) void k_hist_gemm(
        const int* __restrict__ dst, int* __restrict__ bhist,
        const float* __restrict__ x, const float* __restrict__ W,
        __half* __restrict__ h2, int P, int E, int nbin, int N) {
    if ((int)blockIdx.x < nbin) {
        // ---- binhist body ----
        __shared__ int hist[BH];
        for (int b0 = threadIdx.x; b0 < BH; b0 += 256) hist[b0] = 0;
        __syncthreads();
        const int base4 = blockIdx.x * (EPB / 4);
        for (int i = 0; i < EPB / 4 / 256; ++i) {
            int idx = base4 + i * 256 + threadIdx.x;
            int e0 = idx << 2;
            if (e0 + 3 < E) {
                int4 d4 = ((const int4*)dst)[idx];
                atomicAdd(&hist[d4.x >> RSHIFT], 1);
                atomicAdd(&hist[d4.y >> RSHIFT], 1);
                atomicAdd(&hist[d4.z >> RSHIFT], 1);
                atomicAdd(&hist[d4.w >> RSHIFT], 1);
            } else {
                for (int k = 0; k < 4; ++k)
                    if (e0 + k < E) atomicAdd(&hist[dst[e0 + k] >> RSHIFT], 1);
            }
        }
        __syncthreads();
        for (int b0 = threadIdx.x; b0 < P; b0 += 256)
            bhist[blockIdx.x * BH + b0] = hist[b0];
    } else {
        // ---- gemm body (4 threads/row, 16 outputs each) ----
        __shared__ float Wl[DIM * DIM];
        for (int i = threadIdx.x; i < DIM * DIM; i += 256) Wl[i] = W[i];
        __syncthreads();
        int t = ((int)blockIdx.x - nbin) * 256 + threadIdx.x;
        int r = t >> 2;       // row
        int q = t & 3;        // output-feature quarter
        if (r >= N) return;
        const float4* xr4 = (const float4*)(x + (size_t)r * DIM);
        float4 acc[4];
#pragma unroll
        for (int j = 0; j < 4; ++j) acc[j] = make_float4(0.f, 0.f, 0.f, 0.f);
        for (int k0 = 0; k0 < 16; ++k0) {
            float4 xv = xr4[k0];
#pragma unroll
            for (int kk = 0; kk < 4; ++kk) {
                float xs = (&xv.x)[kk];
                const float4* wrow = (const float4*)(Wl + (k0 * 4 + kk) * DIM) + (q << 2);
#pragma unroll
                for (int j = 0; j < 4; ++j) {
                    float4 w = wrow[j];
                    acc[j].x += xs * w.x;
                    acc[j].y += xs * w.y;
                    acc[j].z += xs * w.z;
                    acc[j].w += xs * w.w;
                }
            }
        }
        float4* hr4 = (float4*)(h2 + (size_t)r * DIM) + (q << 1);
        union { __half2 h[4]; float4 f4; } pack;
#pragma unroll
        for (int j = 0; j < 4; j += 2) {
            pack.h[0] = __float22half2_rn(make_float2(acc[j].x, acc[j].y));
            pack.h[1] = __float22half2_rn(make_float2(acc[j].z, acc[j].w));
            pack.h[2] = __float22half2_rn(make_float2(acc[j + 1].x, acc[j + 1].y));
            pack.h[3] = __float22half2_rn(make_float2(acc[j + 1].z, acc[j + 1].w));
            hr4[j >> 1] = pack.f4;
        }
    }
}

// ---------------- binscan: per-bin parallel scan over blocks (grid = P bins) ----------------
// After: bhist[blk*BH+r] = exclusive prefix of bin r over blocks 0..blk-1; bintot[r] = bin total.
__global__ __launch_bounds__(128) void k_binscan(int* __restrict__ bhist,
                                                 int* __restrict__ bintot,
                                                 int nbin) {
    __shared__ int s[128];
    const int r = blockIdx.x;
    int carry = 0;
    for (int base = 0; base < nbin; base += 128) {
        const int idx = base + threadIdx.x;
        int v = (idx < nbin) ? bhist[idx * BH + r] : 0;
        s[threadIdx.x] = v;
        __syncthreads();
        for (int off = 1; off < 128; off <<= 1) {
            int t = (threadIdx.x >= (unsigned)off) ? s[threadIdx.x - off] : 0;
            __syncthreads();
            s[threadIdx.x] += t;
            __syncthreads();
        }
        if (idx < nbin) bhist[idx * BH + r] = carry + s[threadIdx.x] - v;
        carry += s[127];
        __syncthreads();
    }
    if (threadIdx.x == 0) bintot[r] = carry;
}

// ---------------- gscan: exclusive scan of bintot (P <= 512) -> gbase ----------------
__global__ void k_gscan(const int* __restrict__ bintot, int* __restrict__ gbase,
                        int* __restrict__ rowptr, int P, int N, int E) {
    __shared__ int s[512];
    int v = ((int)threadIdx.x < P) ? bintot[threadIdx.x] : 0;
    s[threadIdx.x] = v;
    __syncthreads();
    for (int off = 1; off < 512; off <<= 1) {
        int t = (threadIdx.x >= (unsigned)off) ? s[threadIdx.x - off] : 0;
        __syncthreads();
        s[threadIdx.x] += t;
        __syncthreads();
    }
    if ((int)threadIdx.x < P) gbase[threadIdx.x] = s[threadIdx.x] - v;
    if ((int)threadIdx.x == P - 1) gbase[P] = s[threadIdx.x];  // = E
    if (threadIdx.x == 0) rowptr[N] = E;
}

// ---------------- bin (single pass): group edges by dst-range into block-exclusive runs ----------------
// pk[pos] = (dstlocal << 20) | src   (src < 2^20, dstlocal < 256)
__global__ __launch_bounds__(256) void k_bin(const int* __restrict__ src,
                                             const int* __restrict__ dst,
                                             const int* __restrict__ gbase,
                                             const int* __restrict__ bhist,
                                             int* __restrict__ pk, int P, int E) {
    __shared__ int gofs[BH], lcnt[BH];
    for (int b0 = threadIdx.x; b0 < P; b0 += 256) {
        gofs[b0] = gbase[b0] + bhist[blockIdx.x * BH + b0];
        lcnt[b0] = 0;
    }
    __syncthreads();
    const int base4 = blockIdx.x * (EPB / 4);
    for (int i = 0; i < EPB / 4 / 256; ++i) {
        int idx = base4 + i * 256 + threadIdx.x;
        int e0 = idx << 2;
        if (e0 + 3 < E) {
            int4 d4 = ((const int4*)dst)[idx];
            int4 s4 = ((const int4*)src)[idx];
            int b0;
            b0 = d4.x >> RSHIFT; pk[gofs[b0] + atomicAdd(&lcnt[b0], 1)] = ((d4.x & (RSIZE - 1)) << 20) | s4.x;
            b0 = d4.y >> RSHIFT; pk[gofs[b0] + atomicAdd(&lcnt[b0], 1)] = ((d4.y & (RSIZE - 1)) << 20) | s4.y;
            b0 = d4.z >> RSHIFT; pk[gofs[b0] + atomicAdd(&lcnt[b0], 1)] = ((d4.z & (RSIZE - 1)) << 20) | s4.z;
            b0 = d4.w >> RSHIFT; pk[gofs[b0] + atomicAdd(&lcnt[b0], 1)] = ((d4.w & (RSIZE - 1)) << 20) | s4.w;
        } else {
            for (int k = 0; k < 4; ++k) {
                if (e0 + k < E) {
                    int d = dst[e0 + k];
                    int b0 = d >> RSHIFT;
                    pk[gofs[b0] + atomicAdd(&lcnt[b0], 1)] = ((d & (RSIZE - 1)) << 20) | src[e0 + k];
                }
            }
        }
    }
}

// ---------------- sortrange: per-range LDS counting sort (512 threads for latency hiding) ----------------
__global__ __launch_bounds__(512) void k_sortrange(
        const int* __restrict__ gbase, const int* __restrict__ pk,
        int* __restrict__ ssrc, int* __restrict__ rowptr,
        float* __restrict__ dinv, int N) {
    __shared__ int lhist[256], ls[256], lcur[256];
    const int r = blockIdx.x;
    const int d0 = r << RSHIFT;
    const int tid = threadIdx.x;
    const int i = d0 + tid;   // valid only for tid < 256
    const int ebeg = gbase[r], eend = gbase[r + 1];
    if (tid < 256) lhist[tid] = 0;
    __syncthreads();
    for (int j = ebeg + tid; j < eend; j += 512)
        atomicAdd(&lhist[((unsigned)pk[j]) >> 20], 1);
    __syncthreads();
    int dg = 0;
    if (tid < 256) {
        dg = lhist[tid];
        if (i < N) dinv[i] = rsqrtf((float)dg + 1.0f);  // +1 self-loop
        ls[tid] = dg;
    }
    __syncthreads();
    for (int off = 1; off < 256; off <<= 1) {
        int t = (tid < 256 && tid >= off) ? ls[tid - off] : 0;
        __syncthreads();
        if (tid < 256) ls[tid] += t;
        __syncthreads();
    }
    if (tid < 256) {
        int lofs = ls[tid] - dg;      // local exclusive
        lcur[tid] = ebeg + lofs;      // absolute cursor
        if (i < N) rowptr[i] = ebeg + lofs;
    }
    __syncthreads();
    for (int j = ebeg + tid; j < eend; j += 512) {
        int p = pk[j];
        ssrc[atomicAdd(&lcur[((unsigned)p) >> 20], 1)] = p & 0xFFFFF;
    }
}

// ---------------- nodeagg: node-PAIR pull; 16/8/4/1 cascade; per-edge dinv[src] (scalar loads) ----------------
// acc = sum dinv[s]*h[s]; a = relu((acc + dinv[i]*h[i]) * dinv[i] + b); fp16 out; BN partials.
#define GATHER_BATCH(B)                                                             \
    {                                                                               \
        int sA[B]; float vA[B]; float dA[B];                                        \
        _Pragma("unroll")                                                           \
        for (int k = 0; k < B; ++k) sA[k] = __builtin_amdgcn_readlane(sv, j + k);   \
        _Pragma("unroll")                                                           \
        for (int k = 0; k < B; ++k) vA[k] = __half2float(hb[(size_t)sA[k] * DIM]);  \
        _Pragma("unroll")                                                           \
        for (int k = 0; k < B; ++k) dA[k] = dinv[sA[k]];                            \
        _Pragma("unroll")                                                           \
        for (int k = 0; k < B; ++k) {                                               \
            if (j + k < c) acc0 += vA[k] * dA[k]; else acc1 += vA[k] * dA[k];       \
        }                                                                           \
        j += B;                                                                     \
    }

__global__ __launch_bounds__(256) void k_nodeagg(
        const int* __restrict__ rowptr, const int* __restrict__ ssrc,
        const __half* __restrict__ h2, const float* __restrict__ dinv,
        const float* __restrict__ b, __half* __restrict__ a2,
        float* __restrict__ pstats, int N) {
    const int lane = threadIdx.x & 63;
    const int w = threadIdx.x >> 6;
    const float bl = b[lane];
    const __half* hb = h2 + lane;
    float psum = 0.f, psq = 0.f;
    const int npairs = N >> 1;  // N even (100000)
    for (int t = blockIdx.x * 4 + w; t < npairs; t += ABLK * 4) {
        const int i0 = t << 1;
        const int rb0 = rowptr[i0], rb1 = rowptr[i0 + 1], rb2 = rowptr[i0 + 2];
        const float dv0 = dinv[i0], dv1 = dinv[i0 + 1];
        float acc0 = __half2float(hb[(size_t)i0 * DIM]) * dv0;        // self term node0
        float acc1 = __half2float(hb[(size_t)(i0 + 1) * DIM]) * dv1;  // self term node1
        const int total = rb2 - rb0;
        for (int j0 = 0; j0 < total; j0 += 64) {
            const int m = min(64, total - j0);
            const int c = rb1 - rb0 - j0;   // local boundary (wave-uniform)
            int sv = ssrc[rb0 + j0 + min(lane, m - 1)];
            int j = 0;
            while (j + 16 <= m) GATHER_BATCH(16)
            if (j + 8 <= m) GATHER_BATCH(8)
            if (j + 4 <= m) GATHER_BATCH(4)
            for (; j < m; ++j) {
                int sj = __builtin_amdgcn_readlane(sv, j);
                float v = __half2float(hb[(size_t)sj * DIM]) * dinv[sj];
                if (j < c) acc0 += v; else acc1 += v;
            }
        }
        float a0 = fmaxf(acc0 * dv0 + bl, 0.f);
        float a1 = fmaxf(acc1 * dv1 + bl, 0.f);
        a2[(size_t)i0 * DIM + lane] = __float2half_rn(a0);
        a2[(size_t)(i0 + 1) * DIM + lane] = __float2half_rn(a1);
        psum += a0 + a1;
        psq += a0 * a0 + a1 * a1;
    }
    __shared__ float s1[256], s2[256];
    s1[threadIdx.x] = psum;
    s2[threadIdx.x] = psq;
    __syncthreads();
    if (threadIdx.x < 128) {
        s1[threadIdx.x] += s1[threadIdx.x + 128];
        s2[threadIdx.x] += s2[threadIdx.x + 128];
    }
    __syncthreads();
    if (threadIdx.x < 64) {
        pstats[(size_t)blockIdx.x * 128 + threadIdx.x] = s1[threadIdx.x] + s1[threadIdx.x + 64];
        pstats[(size_t)blockIdx.x * 128 + 64 + threadIdx.x] = s2[threadIdx.x] + s2[threadIdx.x + 64];
    }
}

// ---------------- redstats: stage-1 parallel fold of ABLK partials -> RBLK partials ----------------
__global__ __launch_bounds__(128) void k_redstats(const float* __restrict__ pstats,
                                                  float* __restrict__ pstats2) {
    const int f = threadIdx.x;  // 0..127
    const size_t base = (size_t)blockIdx.x * (ABLK / RBLK) * 128;
    float s = 0.f;
#pragma unroll 8
    for (int j = 0; j < ABLK / RBLK; ++j)
        s += pstats[base + (size_t)j * 128 + f];
    pstats2[(size_t)blockIdx.x * 128 + f] = s;
}

// ---------------- finstats: reduce RBLK partials, emit scale/shift ----------------
__global__ void k_finstats(const float* __restrict__ pstats2,
                           const float* __restrict__ gamma, const float* __restrict__ beta,
                           float* __restrict__ scale, float* __restrict__ shift, int N) {
    __shared__ float ssum[1024], ssq[1024];
    const int f = threadIdx.x & 63;
    const int c = threadIdx.x >> 6;  // 0..15
    float s = 0.f, q = 0.f;
    for (int blk = c; blk < RBLK; blk += 16) {
        s += pstats2[blk * 128 + f];
        q += pstats2[blk * 128 + 64 + f];
    }
    ssum[threadIdx.x] = s;
    ssq[threadIdx.x] = q;
    __syncthreads();
    for (int o = 512; o >= 64; o >>= 1) {
        if ((int)threadIdx.x < o) {
            ssum[threadIdx.x] += ssum[threadIdx.x + o];
            ssq[threadIdx.x] += ssq[threadIdx.x + o];
        }
        __syncthreads();
    }
    if (threadIdx.x < 64) {
        float inv_n = 1.0f / (float)N;
        float mean = ssum[f] * inv_n;
        float var = ssq[f] * inv_n - mean * mean;
        float istd = rsqrtf(var + BN_EPS);
        float sc = gamma[f] * istd;
        scale[f] = sc;
        shift[f] = beta[f] - mean * sc;
    }
}

// ---------------- bn2: out = a2*scale + shift (a2 fp16, already relu'd) ----------------
__global__ void k_bn2(const __half* __restrict__ a2, const float* __restrict__ scale,
                      const float* __restrict__ shift, float* __restrict__ out, int total8) {
    int i = blockIdx.x * blockDim.x + threadIdx.x;
    const int stride = gridDim.x * blockDim.x;  // 262144 ≡ 0 (mod 8)
    const int f8 = i & 7;
    const float4 sc0 = ((const float4*)scale)[f8 * 2];
    const float4 sc1 = ((const float4*)scale)[f8 * 2 + 1];
    const float4 sh0 = ((const float4*)shift)[f8 * 2];
    const float4 sh1 = ((const float4*)shift)[f8 * 2 + 1];
    for (; i < total8; i += stride) {
        union { float4 f; __half2 h[4]; } u;
        u.f = ((const float4*)a2)[i];
        float2 p0 = __half22float2(u.h[0]);
        float2 p1 = __half22float2(u.h[1]);
        float2 p2 = __half22float2(u.h[2]);
        float2 p3 = __half22float2(u.h[3]);
        float4 o0 = make_float4(p0.x * sc0.x + sh0.x, p0.y * sc0.y + sh0.y,
                                p1.x * sc0.z + sh0.z, p1.y * sc0.w + sh0.w);
        float4 o1 = make_float4(p2.x * sc1.x + sh1.x, p2.y * sc1.y + sh1.y,
                                p3.x * sc1.z + sh1.z, p3.y * sc1.w + sh1.w);
        ((float4*)out)[(size_t)i * 2] = o0;
        ((float4*)out)[(size_t)i * 2 + 1] = o1;
    }
}

extern "C" void kernel_launch(void* const* d_in, const int* in_sizes, int n_in,
                              void* d_out, int out_size, void* d_ws, size_t ws_size,
                              hipStream_t stream) {
    const float* x     = (const float*)d_in[0];
    const int*   ei    = (const int*)d_in[1];
    const float* W     = (const float*)d_in[2];
    const float* b     = (const float*)d_in[3];
    const float* gamma = (const float*)d_in[4];
    const float* beta  = (const float*)d_in[5];
    float* out = (float*)d_out;

    const int N = in_sizes[0] / DIM;  // 100000
    const int E = in_sizes[1] / 2;    // 1000000
    const int* esrc = ei;
    const int* edst = ei + E;
    const int P = (N + RSIZE - 1) >> RSHIFT;   // 391 ranges (<= 512)
    const int nbin = (E + EPB - 1) / EPB;      // 489 bin blocks (<= 512)
    const int gemmblocks = (4 * N + 255) / 256;  // 1563

    // workspace layout
    char* ws = (char*)d_ws;
    size_t off = 0;
    int* bhist = (int*)(ws + off);      off += (size_t)nbin * BH * sizeof(int);
    off = (off + 255) & ~(size_t)255;
    int* bintot = (int*)(ws + off);     off += 512 * sizeof(int);
    int* gbase = (int*)(ws + off);      off += 520 * sizeof(int);
    off = (off + 255) & ~(size_t)255;
    float* dinv = (float*)(ws + off);   off += (size_t)N * sizeof(float);
    off = (off + 255) & ~(size_t)255;
    int* rowptr = (int*)(ws + off);     off += (size_t)(N + 1) * sizeof(int);
    off = (off + 255) & ~(size_t)255;
    float* scale = (float*)(ws + off);  off += 64 * sizeof(float);
    float* shift = (float*)(ws + off);  off += 64 * sizeof(float);
    off = (off + 255) & ~(size_t)255;
    float* pstats = (float*)(ws + off); off += (size_t)ABLK * 128 * sizeof(float);
    off = (off + 255) & ~(size_t)255;
    float* pstats2 = (float*)(ws + off); off += (size_t)RBLK * 128 * sizeof(float);
    off = (off + 255) & ~(size_t)255;
    int* pk = (int*)(ws + off);         off += (size_t)E * sizeof(int);
    off = (off + 255) & ~(size_t)255;
    int* ssrc = (int*)(ws + off);       off += (size_t)E * sizeof(int);
    off = (off + 255) & ~(size_t)255;
    __half* h2 = (__half*)(ws + off);   off += (size_t)N * DIM * sizeof(__half);
    off = (off + 255) & ~(size_t)255;
    __half* a2 = (__half*)(ws + off);   off += (size_t)N * DIM * sizeof(__half);

    k_hist_gemm<<<nbin + gemmblocks, 256, 0, stream>>>(edst, bhist, x, W, h2, P, E, nbin, N);
    k_binscan<<<P, 128, 0, stream>>>(bhist, bintot, nbin);
    k_gscan<<<1, 512, 0, stream>>>(bintot, gbase, rowptr, P, N, E);
    k_bin<<<nbin, 256, 0, stream>>>(esrc, edst, gbase, bhist, pk, P, E);
    k_sortrange<<<P, 512, 0, stream>>>(gbase, pk, ssrc, rowptr, dinv, N);
    k_nodeagg<<<ABLK, 256, 0, stream>>>(rowptr, ssrc, h2, dinv, b, a2, pstats, N);
    k_redstats<<<RBLK, 128, 0, stream>>>(pstats, pstats2);
    k_finstats<<<1, 1024, 0, stream>>>(pstats2, gamma, beta, scale, shift, N);
    k_bn2<<<1024, 256, 0, stream>>>(a2, scale, shift, out, N * DIM / 8);
}